// Round 3
// baseline (425.788 us; speedup 1.0000x reference)
//
#include <hip/hip_runtime.h>
#include <cstdint>
#include <cstddef>

#define SEQ   2048
#define EDIM  256
#define FFND  512
#define NBATCH 16

typedef unsigned short u16;
typedef __attribute__((ext_vector_type(8))) __bf16 bf16x8;
typedef __attribute__((ext_vector_type(4))) float f32x4;

__device__ __forceinline__ float bf2f(u16 u) {
  union { unsigned int w; float f; } v; v.w = ((unsigned int)u) << 16; return v.f;
}
__device__ __forceinline__ u16 f2bf(float f) {
  union { float f; unsigned int w; } v; v.f = f;
  unsigned int r = v.w + 0x7fffu + ((v.w >> 16) & 1u);
  return (u16)(r >> 16);
}

// -------- sniff: decide whether float inputs are f32 (flag=1) or bf16 (flag=0) --------
// True-bf16 data: every u16 is a small bf16 (exp field <= ~123 for N(0,0.02)).
// f32 data read as u16 pairs: low halves are mantissa garbage -> ~half have exp > 128.
__global__ void sniff_kernel(const void* embed, int* flag) {
  int t = threadIdx.x;
  const u16* p = (const u16*)embed;
  int c = 0;
  #pragma unroll
  for (int j = 0; j < 8; ++j) {
    u16 v = p[t * 8 + j];
    int e = (v >> 7) & 0xff;
    c += (e > 128) ? 1 : 0;
  }
  #pragma unroll
  for (int d = 1; d < 64; d <<= 1) c += __shfl_xor(c, d);
  if (t == 0) *flag = (c > 64) ? 1 : 0;
}

// -------- canonicalize all small float params to bf16 in ws --------
struct CanonArgs { const void* p[14]; };

__global__ void canon_kernel(CanonArgs a, const int* __restrict__ flag, u16* __restrict__ dst) {
  const int off[15] = {0, 128, 131200, 131712, 131728, 139920, 140944, 403088,
                       403600, 404112, 404624, 405136, 405648, 406160, 406162};
  int i = blockIdx.x * 256 + threadIdx.x;
  if (i >= 406162) return;
  int isf32 = *flag;
  int s = 0;
  #pragma unroll
  for (int k = 0; k < 13; ++k) s += (i >= off[k + 1]) ? 1 : 0;
  int j = i - off[s];
  u16 v = isf32 ? f2bf(((const float*)a.p[s])[j]) : ((const u16*)a.p[s])[j];
  dst[i] = v;
}

// ---------------- prep: transpose canonical weights to [n][k] (k-contiguous) ----------------
__global__ void prep_kernel(const u16* __restrict__ cw, const u16* __restrict__ l2,
                            u16* __restrict__ cwT, u16* __restrict__ l2T) {
  int id = blockIdx.x * 256 + threadIdx.x;
  if (id < 2 * 256 * 256) {
    int l = id >> 16, rem = id & 65535;
    int n = rem >> 8, k = rem & 255;
    cwT[id] = cw[l * 65536 + k * 256 + n];
  } else {
    int j = id - 131072;
    if (j < 2 * 512 * 256) {
      int l = j >> 17, rem = j & 131071;
      int n = rem >> 9, k = rem & 511;
      l2T[j] = l2[l * 131072 + k * 256 + n];
    }
  }
}

// ---------------- embed + positional encoding -> x (bf16), dual-dtype gather ----------------
__global__ void embed_kernel(const int* __restrict__ tokens, const void* __restrict__ embed,
                             const int* __restrict__ flag, u16* __restrict__ x) {
  int t = threadIdx.x;
  int m = blockIdx.x * 4 + (t >> 6);
  int e0 = (t & 63) * 4;
  int tok = tokens[m];
  float ev[4];
  if (*flag) {
    float4 v = *reinterpret_cast<const float4*>((const float*)embed + (size_t)tok * EDIM + e0);
    ev[0] = v.x; ev[1] = v.y; ev[2] = v.z; ev[3] = v.w;
  } else {
    uint2 v = *reinterpret_cast<const uint2*>((const u16*)embed + (size_t)tok * EDIM + e0);
    ev[0] = bf2f((u16)(v.x & 0xffff)); ev[1] = bf2f((u16)(v.x >> 16));
    ev[2] = bf2f((u16)(v.y & 0xffff)); ev[3] = bf2f((u16)(v.y >> 16));
  }
  int s = m & (SEQ - 1);
  const float c0 = 9.210340371976184f / 128.f;  // ln(10000)/128
  u16 o[4];
  #pragma unroll
  for (int j = 0; j < 4; ++j) {
    int e = e0 + j;
    int i = e >> 1;
    float freq = expf(-(float)i * c0);
    float ang = (float)s * freq;
    float pe = (e & 1) ? cosf(ang) : sinf(ang);
    o[j] = f2bf(ev[j] + pe);
  }
  *reinterpret_cast<uint2*>(x + (size_t)m * EDIM + e0) = *reinterpret_cast<const uint2*>(o);
}

// ---------------- A = bf16(cos(x + theta_tiled)) ----------------
__global__ void cos_a_kernel(const u16* __restrict__ x, const u16* __restrict__ theta,
                             u16* __restrict__ a) {
  size_t idx = (size_t)blockIdx.x * 256 + threadIdx.x;
  size_t base = idx * 8;
  int e0 = (int)(base & (EDIM - 1));
  uint4 xv = *reinterpret_cast<const uint4*>(x + base);
  const u16* xs = reinterpret_cast<const u16*>(&xv);
  u16 o[8];
  #pragma unroll
  for (int j = 0; j < 8; ++j) {
    float th = bf2f(theta[(e0 + j) & 63]);   // theta tiled with period DK=64
    o[j] = f2bf(cosf(bf2f(xs[j]) + th));
  }
  *reinterpret_cast<uint4*>(a + base) = *reinterpret_cast<const uint4*>(o);
}

// ------- fused GEMM (A[M,K]bf16 x BT[N=256,K]bf16) + bias + residual + LN, x in bf16 -------
template<int K>
__launch_bounds__(256, 3)
__global__ void gemm_ln_kernel(const u16* __restrict__ A, const u16* __restrict__ BT,
                               const u16* __restrict__ bias, const u16* __restrict__ gamma,
                               const u16* __restrict__ beta, u16* __restrict__ x) {
  __shared__ u16 At[64 * 64];        // 8 KB
  __shared__ u16 Bt[256 * 64];       // 32 KB
  __shared__ float2 sstat[64][5];    // cross-wave LN partials (+pad col)
  __shared__ float2 sms[64];         // mean, rstd

  const int tid = threadIdx.x;
  const int wave = tid >> 6, lane = tid & 63;
  const int m0 = blockIdx.x * 64;
  const int fr = lane & 15, fq = lane >> 4;

  f32x4 acc[4][4];
  #pragma unroll
  for (int i = 0; i < 4; ++i)
    #pragma unroll
    for (int j = 0; j < 4; ++j)
      acc[i][j] = {0.f, 0.f, 0.f, 0.f};

  for (int k0 = 0; k0 < K; k0 += 64) {
    // explicit staging: global uint4 load -> ds_write_b128 (every LDS byte written)
    const u16* asrc = A + (size_t)m0 * K + k0;
    const u16* bsrc = BT + k0;
    uint4 ga[2], gb[8];
    #pragma unroll
    for (int it = 0; it < 2; ++it) {
      int chunk = tid + it * 256;
      ga[it] = *reinterpret_cast<const uint4*>(asrc + (size_t)(chunk >> 3) * K + (chunk & 7) * 8);
    }
    #pragma unroll
    for (int it = 0; it < 8; ++it) {
      int chunk = tid + it * 256;
      gb[it] = *reinterpret_cast<const uint4*>(bsrc + (size_t)(chunk >> 3) * K + (chunk & 7) * 8);
    }
    #pragma unroll
    for (int it = 0; it < 2; ++it)
      *reinterpret_cast<uint4*>(At + (tid + it * 256) * 8) = ga[it];
    #pragma unroll
    for (int it = 0; it < 8; ++it)
      *reinterpret_cast<uint4*>(Bt + (tid + it * 256) * 8) = gb[it];
    __syncthreads();

    const bf16x8* Ap = reinterpret_cast<const bf16x8*>(At);
    const bf16x8* Bp = reinterpret_cast<const bf16x8*>(Bt);
    #pragma unroll
    for (int ks = 0; ks < 2; ++ks) {
      bf16x8 af[4], bfv[4];
      #pragma unroll
      for (int mi = 0; mi < 4; ++mi)
        af[mi] = Ap[(mi * 16 + fr) * 8 + ks * 4 + fq];              // A[m=lane&15][k=quad*8+j]
      #pragma unroll
      for (int ni = 0; ni < 4; ++ni)
        bfv[ni] = Bp[(wave * 64 + ni * 16 + fr) * 8 + ks * 4 + fq]; // B[n=lane&15][k=quad*8+j]
      #pragma unroll
      for (int mi = 0; mi < 4; ++mi)
        #pragma unroll
        for (int ni = 0; ni < 4; ++ni)
          acc[mi][ni] = __builtin_amdgcn_mfma_f32_16x16x32_bf16(af[mi], bfv[ni], acc[mi][ni], 0, 0, 0);
    }
    __syncthreads();
  }

  // ---- register-resident epilogue ----
  // C/D layout (m89-verified): row = mi*16 + fq*4 + rg, col = wave*64 + ni*16 + fr
  int cols[4];
  float bcol[4];
  #pragma unroll
  for (int ni = 0; ni < 4; ++ni) {
    cols[ni] = wave * 64 + ni * 16 + fr;
    bcol[ni] = bf2f(bias[cols[ni]]);
  }
  #pragma unroll
  for (int mi = 0; mi < 4; ++mi)
    #pragma unroll
    for (int rg = 0; rg < 4; ++rg) {
      int row = m0 + mi * 16 + fq * 4 + rg;
      #pragma unroll
      for (int ni = 0; ni < 4; ++ni)
        acc[mi][ni][rg] += bf2f(x[(size_t)row * EDIM + cols[ni]]) + bcol[ni];
    }
  // per-row LN stats: partials over 4 cols, butterfly over fr lanes, cross-wave via LDS
  float sr[4][4], sq[4][4];
  #pragma unroll
  for (int mi = 0; mi < 4; ++mi)
    #pragma unroll
    for (int rg = 0; rg < 4; ++rg) {
      float a = 0.f, b = 0.f;
      #pragma unroll
      for (int ni = 0; ni < 4; ++ni) {
        float t = acc[mi][ni][rg];
        a += t; b += t * t;
      }
      sr[mi][rg] = a; sq[mi][rg] = b;
    }
  #pragma unroll
  for (int d = 1; d < 16; d <<= 1)
    #pragma unroll
    for (int mi = 0; mi < 4; ++mi)
      #pragma unroll
      for (int rg = 0; rg < 4; ++rg) {
        sr[mi][rg] += __shfl_xor(sr[mi][rg], d);
        sq[mi][rg] += __shfl_xor(sq[mi][rg], d);
      }
  if (fr == 0) {
    #pragma unroll
    for (int mi = 0; mi < 4; ++mi)
      #pragma unroll
      for (int rg = 0; rg < 4; ++rg)
        sstat[mi * 16 + fq * 4 + rg][wave] = float2{sr[mi][rg], sq[mi][rg]};
  }
  __syncthreads();
  if (tid < 64) {
    float s = 0.f, s2 = 0.f;
    #pragma unroll
    for (int w = 0; w < 4; ++w) {
      float2 p = sstat[tid][w];
      s += p.x; s2 += p.y;
    }
    float mean = s * (1.f / 256.f);
    float var = fmaxf(s2 * (1.f / 256.f) - mean * mean, 0.f);
    sms[tid] = float2{mean, rsqrtf(var + 1e-5f)};
  }
  __syncthreads();
  float gcol[4], btcol[4];
  #pragma unroll
  for (int ni = 0; ni < 4; ++ni) {
    gcol[ni] = bf2f(gamma[cols[ni]]);
    btcol[ni] = bf2f(beta[cols[ni]]);
  }
  #pragma unroll
  for (int mi = 0; mi < 4; ++mi)
    #pragma unroll
    for (int rg = 0; rg < 4; ++rg) {
      int lrow = mi * 16 + fq * 4 + rg;
      float2 ms = sms[lrow];
      int row = m0 + lrow;
      #pragma unroll
      for (int ni = 0; ni < 4; ++ni) {
        float o = (acc[mi][ni][rg] - ms.x) * ms.y * gcol[ni] + btcol[ni];
        x[(size_t)row * EDIM + cols[ni]] = f2bf(o);
      }
    }
}

// ---------------- h = relu(q @ lin1_w + b1), q = cos(x[:, :8]) * cos(ffn_theta) ----------------
__global__ void h_kernel(const u16* __restrict__ x, const u16* __restrict__ ffn_theta,
                         const u16* __restrict__ w1, const u16* __restrict__ b1,
                         u16* __restrict__ h) {
  int tid = threadIdx.x;
  int m = blockIdx.x * 2 + (tid >> 7);
  int f0 = (tid & 127) * 4;
  uint4 xv = *reinterpret_cast<const uint4*>(x + (size_t)m * EDIM);  // first 8 bf16 of row
  const u16* xs = reinterpret_cast<const u16*>(&xv);
  float q[8];
  #pragma unroll
  for (int n = 0; n < 8; ++n) q[n] = cosf(bf2f(xs[n])) * cosf(bf2f(ffn_theta[n]));
  float acc[4];
  #pragma unroll
  for (int j = 0; j < 4; ++j) acc[j] = bf2f(b1[f0 + j]);
  #pragma unroll
  for (int n = 0; n < 8; ++n) {
    uint2 wv = *reinterpret_cast<const uint2*>(w1 + n * FFND + f0);
    acc[0] += q[n] * bf2f((u16)(wv.x & 0xffff));
    acc[1] += q[n] * bf2f((u16)(wv.x >> 16));
    acc[2] += q[n] * bf2f((u16)(wv.y & 0xffff));
    acc[3] += q[n] * bf2f((u16)(wv.y >> 16));
  }
  u16 o[4];
  #pragma unroll
  for (int j = 0; j < 4; ++j) o[j] = f2bf(fmaxf(acc[j], 0.f));
  *reinterpret_cast<uint2*>(h + (size_t)m * FFND + f0) = *reinterpret_cast<const uint2*>(o);
}

// ---------------- mean pool over S (pooled holds SUM; divided in logits) ----------------
__global__ void pool_kernel(const u16* __restrict__ x, float* __restrict__ pooled) {
  int b = blockIdx.x >> 5, c = blockIdx.x & 31;
  int t = threadIdx.x;
  const u16* base = x + ((size_t)b * SEQ + (size_t)c * 64) * EDIM + t;
  float s = 0.f;
  #pragma unroll 8
  for (int j = 0; j < 64; ++j) s += bf2f(base[(size_t)j * EDIM]);
  atomicAdd(&pooled[b * EDIM + t], s);
}

__global__ void logits_kernel(const float* __restrict__ pooled, const u16* __restrict__ clsw,
                              const u16* __restrict__ clsb, const int* __restrict__ flag,
                              void* __restrict__ out) {
  int t = threadIdx.x;
  if (t >= 32) return;
  int b = t >> 1, c = t & 1;
  float s = 0.f;
  for (int e = 0; e < 256; ++e) s += pooled[b * 256 + e] * bf2f(clsw[e * 2 + c]);
  s = s * (1.f / 2048.f) + bf2f(clsb[c]);
  if (*flag) ((float*)out)[b * 2 + c] = s;
  else       ((u16*)out)[b * 2 + c] = f2bf(s);
}

extern "C" void kernel_launch(void* const* d_in, const int* in_sizes, int n_in,
                              void* d_out, int out_size, void* d_ws, size_t ws_size,
                              hipStream_t stream) {
  const int* tokens = (const int*)d_in[0];

  // ws layout (50 MB total):
  char* ws = (char*)d_ws;
  u16*   canon  = (u16*)(ws + 0);              //   812,324 B used (406,162 u16), pad to 1 MB
  u16*   cwT    = (u16*)(ws + 1048576);        //   262,144 B
  u16*   l2T    = (u16*)(ws + 1310720);        //   524,288 B
  float* pooled = (float*)(ws + 1835008);      //    16,384 B
  int*   flag   = (int*)(ws + 1851392);        //         4 B
  u16*   x      = (u16*)(ws + 2097152);        // 16,777,216 B  [32768][256] bf16
  u16*   buf    = (u16*)(ws + 18874368);       // 33,554,432 B  a_attn / h

  // canonical param offsets (elems)
  u16* c_attn = canon + 0;
  u16* c_cw   = canon + 128;
  u16* c_cb   = canon + 131200;
  u16* c_ft   = canon + 131712;
  u16* c_l1w  = canon + 131728;
  u16* c_l1b  = canon + 139920;
  u16* c_l2w  = canon + 140944;
  u16* c_l2b  = canon + 403088;
  u16* c_ln1g = canon + 403600;
  u16* c_ln1b = canon + 404112;
  u16* c_ln2g = canon + 404624;
  u16* c_ln2b = canon + 405136;
  u16* c_clsw = canon + 405648;
  u16* c_clsb = canon + 406160;

  sniff_kernel<<<1, 64, 0, stream>>>(d_in[1], flag);

  CanonArgs ca;
  for (int i = 0; i < 14; ++i) ca.p[i] = d_in[i + 2];
  canon_kernel<<<1587, 256, 0, stream>>>(ca, flag, canon);

  prep_kernel<<<1536, 256, 0, stream>>>(c_cw, c_l2w, cwT, l2T);
  embed_kernel<<<8192, 256, 0, stream>>>(tokens, d_in[1], flag, x);

  for (int l = 0; l < 2; ++l) {
    cos_a_kernel<<<4096, 256, 0, stream>>>(x, c_attn + l * 64, buf);
    gemm_ln_kernel<256><<<512, 256, 0, stream>>>(buf, cwT + l * 65536, c_cb + l * 256,
                                                 c_ln1g + l * 256, c_ln1b + l * 256, x);
    h_kernel<<<16384, 256, 0, stream>>>(x, c_ft + l * 8, c_l1w + l * 4096, c_l1b + l * 512, buf);
    gemm_ln_kernel<512><<<512, 256, 0, stream>>>(buf, l2T + l * 131072, c_l2b + l * 256,
                                                 c_ln2g + l * 256, c_ln2b + l * 256, x);
  }

  hipMemsetAsync(pooled, 0, NBATCH * EDIM * sizeof(float), stream);
  pool_kernel<<<512, 256, 0, stream>>>(x, pooled);
  logits_kernel<<<1, 64, 0, stream>>>(pooled, c_clsw, c_clsb, flag, d_out);
}

// Round 4
// 334.541 us; speedup vs baseline: 1.2728x; 1.2728x over previous
//
#include <hip/hip_runtime.h>
#include <cstdint>
#include <cstddef>

#define SEQ   2048
#define EDIM  256
#define FFND  512
#define NBATCH 16

typedef unsigned short u16;
typedef __attribute__((ext_vector_type(8))) __bf16 bf16x8;
typedef __attribute__((ext_vector_type(4))) float f32x4;

__device__ __forceinline__ float bf2f(u16 u) {
  union { unsigned int w; float f; } v; v.w = ((unsigned int)u) << 16; return v.f;
}
__device__ __forceinline__ u16 f2bf(float f) {
  union { float f; unsigned int w; } v; v.f = f;
  unsigned int r = v.w + 0x7fffu + ((v.w >> 16) & 1u);
  return (u16)(r >> 16);
}
// hardware cos: v_cos_f32 takes revolutions; explicit fract keeps it in-range
__device__ __forceinline__ float fast_cos(float x) {
  float r = x * 0.15915494309189535f;
  r = r - floorf(r);
  return __builtin_amdgcn_cosf(r);
}

// -------- sniff: float inputs f32 (flag=1) or bf16 (flag=0) --------
__global__ void sniff_kernel(const void* embed, int* flag) {
  int t = threadIdx.x;
  const u16* p = (const u16*)embed;
  int c = 0;
  #pragma unroll
  for (int j = 0; j < 8; ++j) {
    u16 v = p[t * 8 + j];
    int e = (v >> 7) & 0xff;
    c += (e > 128) ? 1 : 0;
  }
  #pragma unroll
  for (int d = 1; d < 64; d <<= 1) c += __shfl_xor(c, d);
  if (t == 0) *flag = (c > 64) ? 1 : 0;
}

// -------- canonicalize all small float params to bf16 in ws --------
struct CanonArgs { const void* p[14]; };

__global__ void canon_kernel(CanonArgs a, const int* __restrict__ flag, u16* __restrict__ dst) {
  const int off[15] = {0, 128, 131200, 131712, 131728, 139920, 140944, 403088,
                       403600, 404112, 404624, 405136, 405648, 406160, 406162};
  int i = blockIdx.x * 256 + threadIdx.x;
  if (i >= 406162) return;
  int isf32 = *flag;
  int s = 0;
  #pragma unroll
  for (int k = 0; k < 13; ++k) s += (i >= off[k + 1]) ? 1 : 0;
  int j = i - off[s];
  u16 v = isf32 ? f2bf(((const float*)a.p[s])[j]) : ((const u16*)a.p[s])[j];
  dst[i] = v;
}

// ---------------- prep: transpose weights to [n][k] ----------------
__global__ void prep_kernel(const u16* __restrict__ cw, const u16* __restrict__ l2,
                            u16* __restrict__ cwT, u16* __restrict__ l2T) {
  int id = blockIdx.x * 256 + threadIdx.x;
  if (id < 2 * 256 * 256) {
    int l = id >> 16, rem = id & 65535;
    int n = rem >> 8, k = rem & 255;
    cwT[id] = cw[l * 65536 + k * 256 + n];
  } else {
    int j = id - 131072;
    if (j < 2 * 512 * 256) {
      int l = j >> 17, rem = j & 131071;
      int n = rem >> 9, k = rem & 511;
      l2T[j] = l2[l * 131072 + k * 256 + n];
    }
  }
}

// ---------------- embed + positional encoding -> x (bf16) ----------------
__global__ void embed_kernel(const int* __restrict__ tokens, const void* __restrict__ embed,
                             const int* __restrict__ flag, u16* __restrict__ x) {
  int t = threadIdx.x;
  int m = blockIdx.x * 4 + (t >> 6);
  int e0 = (t & 63) * 4;
  int tok = tokens[m];
  float ev[4];
  if (*flag) {
    float4 v = *reinterpret_cast<const float4*>((const float*)embed + (size_t)tok * EDIM + e0);
    ev[0] = v.x; ev[1] = v.y; ev[2] = v.z; ev[3] = v.w;
  } else {
    uint2 v = *reinterpret_cast<const uint2*>((const u16*)embed + (size_t)tok * EDIM + e0);
    ev[0] = bf2f((u16)(v.x & 0xffff)); ev[1] = bf2f((u16)(v.x >> 16));
    ev[2] = bf2f((u16)(v.y & 0xffff)); ev[3] = bf2f((u16)(v.y >> 16));
  }
  int s = m & (SEQ - 1);
  const float c0 = 9.210340371976184f / 128.f;  // ln(10000)/128
  const float inv2pi = 0.15915494309189535f;
  u16 o[4];
  #pragma unroll
  for (int j = 0; j < 4; ++j) {
    int e = e0 + j;
    int i = e >> 1;
    float revfreq = __expf(-(float)i * c0) * inv2pi;
    float rev = (float)s * revfreq;
    rev = rev - floorf(rev);
    float pe = (e & 1) ? __builtin_amdgcn_cosf(rev) : __builtin_amdgcn_sinf(rev);
    o[j] = f2bf(ev[j] + pe);
  }
  *reinterpret_cast<uint2*>(x + (size_t)m * EDIM + e0) = *reinterpret_cast<const uint2*>(o);
}

// ------- fused GEMM (A x BT[N=256,K]) + bias + residual + LN; FUSE: A=cos(x+theta) -------
template<int K, bool FUSE>
__launch_bounds__(256, 3)
__global__ void gemm_ln_kernel(const u16* A, const u16* __restrict__ BT,
                               const u16* __restrict__ bias, const u16* __restrict__ gamma,
                               const u16* __restrict__ beta, const u16* __restrict__ theta,
                               u16* x) {
  __shared__ u16 At[64 * 64];        // 8 KB
  __shared__ u16 Bt[256 * 64];       // 32 KB
  __shared__ float2 sstat[64][5];
  __shared__ float2 sms[64];

  const int tid = threadIdx.x;
  const int wave = tid >> 6, lane = tid & 63;
  const int m0 = blockIdx.x * 64;
  const int fr = lane & 15, fq = lane >> 4;

  float th[8];
  if (FUSE) {
    #pragma unroll
    for (int j = 0; j < 8; ++j) th[j] = bf2f(theta[(tid & 7) * 8 + j]);  // k&63 slice
  }

  f32x4 acc[4][4];
  #pragma unroll
  for (int i = 0; i < 4; ++i)
    #pragma unroll
    for (int j = 0; j < 4; ++j)
      acc[i][j] = {0.f, 0.f, 0.f, 0.f};

  for (int k0 = 0; k0 < K; k0 += 64) {
    const u16* asrc = A + (size_t)m0 * K + k0;
    const u16* bsrc = BT + k0;
    uint4 ga[2], gb[8];
    #pragma unroll
    for (int it = 0; it < 2; ++it) {
      int chunk = tid + it * 256;
      ga[it] = *reinterpret_cast<const uint4*>(asrc + (size_t)(chunk >> 3) * K + (chunk & 7) * 8);
    }
    #pragma unroll
    for (int it = 0; it < 8; ++it) {
      int chunk = tid + it * 256;
      gb[it] = *reinterpret_cast<const uint4*>(bsrc + (size_t)(chunk >> 3) * K + (chunk & 7) * 8);
    }
    if (FUSE) {
      #pragma unroll
      for (int it = 0; it < 2; ++it) {
        u16* gp = reinterpret_cast<u16*>(&ga[it]);
        #pragma unroll
        for (int j = 0; j < 8; ++j)
          gp[j] = f2bf(fast_cos(bf2f(gp[j]) + th[j]));
      }
    }
    #pragma unroll
    for (int it = 0; it < 2; ++it)
      *reinterpret_cast<uint4*>(At + (tid + it * 256) * 8) = ga[it];
    #pragma unroll
    for (int it = 0; it < 8; ++it)
      *reinterpret_cast<uint4*>(Bt + (tid + it * 256) * 8) = gb[it];
    __syncthreads();

    const bf16x8* Ap = reinterpret_cast<const bf16x8*>(At);
    const bf16x8* Bp = reinterpret_cast<const bf16x8*>(Bt);
    #pragma unroll
    for (int ks = 0; ks < 2; ++ks) {
      bf16x8 af[4], bfv[4];
      #pragma unroll
      for (int mi = 0; mi < 4; ++mi)
        af[mi] = Ap[(mi * 16 + fr) * 8 + ks * 4 + fq];
      #pragma unroll
      for (int ni = 0; ni < 4; ++ni)
        bfv[ni] = Bp[(wave * 64 + ni * 16 + fr) * 8 + ks * 4 + fq];
      #pragma unroll
      for (int mi = 0; mi < 4; ++mi)
        #pragma unroll
        for (int ni = 0; ni < 4; ++ni)
          acc[mi][ni] = __builtin_amdgcn_mfma_f32_16x16x32_bf16(af[mi], bfv[ni], acc[mi][ni], 0, 0, 0);
    }
    __syncthreads();
  }

  // ---- register-resident epilogue (C/D: row=mi*16+fq*4+rg, col=wave*64+ni*16+fr) ----
  int cols[4];
  float bcol[4];
  #pragma unroll
  for (int ni = 0; ni < 4; ++ni) {
    cols[ni] = wave * 64 + ni * 16 + fr;
    bcol[ni] = bf2f(bias[cols[ni]]);
  }
  #pragma unroll
  for (int mi = 0; mi < 4; ++mi)
    #pragma unroll
    for (int rg = 0; rg < 4; ++rg) {
      int row = m0 + mi * 16 + fq * 4 + rg;
      #pragma unroll
      for (int ni = 0; ni < 4; ++ni)
        acc[mi][ni][rg] += bf2f(x[(size_t)row * EDIM + cols[ni]]) + bcol[ni];
    }
  float sr[4][4], sq[4][4];
  #pragma unroll
  for (int mi = 0; mi < 4; ++mi)
    #pragma unroll
    for (int rg = 0; rg < 4; ++rg) {
      float a = 0.f, b = 0.f;
      #pragma unroll
      for (int ni = 0; ni < 4; ++ni) {
        float t2 = acc[mi][ni][rg];
        a += t2; b += t2 * t2;
      }
      sr[mi][rg] = a; sq[mi][rg] = b;
    }
  #pragma unroll
  for (int d = 1; d < 16; d <<= 1)
    #pragma unroll
    for (int mi = 0; mi < 4; ++mi)
      #pragma unroll
      for (int rg = 0; rg < 4; ++rg) {
        sr[mi][rg] += __shfl_xor(sr[mi][rg], d);
        sq[mi][rg] += __shfl_xor(sq[mi][rg], d);
      }
  if (fr == 0) {
    #pragma unroll
    for (int mi = 0; mi < 4; ++mi)
      #pragma unroll
      for (int rg = 0; rg < 4; ++rg)
        sstat[mi * 16 + fq * 4 + rg][wave] = float2{sr[mi][rg], sq[mi][rg]};
  }
  __syncthreads();
  if (tid < 64) {
    float s = 0.f, s2 = 0.f;
    #pragma unroll
    for (int w = 0; w < 4; ++w) {
      float2 p = sstat[tid][w];
      s += p.x; s2 += p.y;
    }
    float mean = s * (1.f / 256.f);
    float var = fmaxf(s2 * (1.f / 256.f) - mean * mean, 0.f);
    sms[tid] = float2{mean, rsqrtf(var + 1e-5f)};
  }
  __syncthreads();
  float gcol[4], btcol[4];
  #pragma unroll
  for (int ni = 0; ni < 4; ++ni) {
    gcol[ni] = bf2f(gamma[cols[ni]]);
    btcol[ni] = bf2f(beta[cols[ni]]);
  }
  #pragma unroll
  for (int mi = 0; mi < 4; ++mi)
    #pragma unroll
    for (int rg = 0; rg < 4; ++rg) {
      int lrow = mi * 16 + fq * 4 + rg;
      float2 ms = sms[lrow];
      int row = m0 + lrow;
      #pragma unroll
      for (int ni = 0; ni < 4; ++ni) {
        float o = (acc[mi][ni][rg] - ms.x) * ms.y * gcol[ni] + btcol[ni];
        x[(size_t)row * EDIM + cols[ni]] = f2bf(o);
      }
    }
}

// ------- h = relu(q @ lin1_w + b1); q computed ONCE per row into LDS -------
__global__ void h_kernel(const u16* __restrict__ x, const u16* __restrict__ ffn_theta,
                         const u16* __restrict__ w1, const u16* __restrict__ b1,
                         u16* __restrict__ h) {
  __shared__ float qs[32][8];   // 1 KB
  const int tid = threadIdx.x;
  const int m0 = blockIdx.x * 32;
  // phase 1: q[r][n] = cos(x[r][n]) * cos(theta[n]) — one thread per (r,n)
  {
    int r = tid >> 3, n = tid & 7;
    float xv = bf2f(x[(size_t)(m0 + r) * EDIM + n]);
    qs[r][n] = fast_cos(xv) * fast_cos(bf2f(ffn_theta[n]));
  }
  __syncthreads();
  // phase 2: thread owns cols c0..c0+7, rows rg, rg+4, ... (8 rows)
  const int c0 = (tid & 63) * 8, rg = tid >> 6;
  float wf[8][8];
  #pragma unroll
  for (int n = 0; n < 8; ++n) {
    uint4 wv = *reinterpret_cast<const uint4*>(w1 + n * FFND + c0);
    const u16* wp = reinterpret_cast<const u16*>(&wv);
    #pragma unroll
    for (int j = 0; j < 8; ++j) wf[n][j] = bf2f(wp[j]);
  }
  float bv[8];
  {
    uint4 bvv = *reinterpret_cast<const uint4*>(b1 + c0);
    const u16* bp = reinterpret_cast<const u16*>(&bvv);
    #pragma unroll
    for (int j = 0; j < 8; ++j) bv[j] = bf2f(bp[j]);
  }
  for (int r = rg; r < 32; r += 4) {
    float4 qa = *reinterpret_cast<const float4*>(&qs[r][0]);
    float4 qb = *reinterpret_cast<const float4*>(&qs[r][4]);
    float qv[8] = {qa.x, qa.y, qa.z, qa.w, qb.x, qb.y, qb.z, qb.w};
    float acc[8];
    #pragma unroll
    for (int j = 0; j < 8; ++j) acc[j] = bv[j];
    #pragma unroll
    for (int n = 0; n < 8; ++n)
      #pragma unroll
      for (int j = 0; j < 8; ++j)
        acc[j] += qv[n] * wf[n][j];
    u16 o[8];
    #pragma unroll
    for (int j = 0; j < 8; ++j) o[j] = f2bf(fmaxf(acc[j], 0.f));
    *reinterpret_cast<uint4*>(h + (size_t)(m0 + r) * FFND + c0) = *reinterpret_cast<const uint4*>(o);
  }
}

// ---------------- mean pool over S (pooled holds SUM) ----------------
__global__ void pool_kernel(const u16* __restrict__ x, float* __restrict__ pooled) {
  int b = blockIdx.x >> 5, rq = blockIdx.x & 31;
  int t = threadIdx.x;
  int c4 = (t & 63) * 4, rg = t >> 6;
  const u16* base = x + ((size_t)b * SEQ + rq * 64 + rg) * EDIM + c4;
  float s0 = 0.f, s1 = 0.f, s2 = 0.f, s3 = 0.f;
  #pragma unroll 4
  for (int j = 0; j < 16; ++j) {
    uint2 v = *reinterpret_cast<const uint2*>(base + (size_t)j * 4 * EDIM);
    s0 += bf2f((u16)(v.x & 0xffff)); s1 += bf2f((u16)(v.x >> 16));
    s2 += bf2f((u16)(v.y & 0xffff)); s3 += bf2f((u16)(v.y >> 16));
  }
  float* p = pooled + b * EDIM + c4;
  atomicAdd(p + 0, s0); atomicAdd(p + 1, s1);
  atomicAdd(p + 2, s2); atomicAdd(p + 3, s3);
}

__global__ void logits_kernel(const float* __restrict__ pooled, const u16* __restrict__ clsw,
                              const u16* __restrict__ clsb, const int* __restrict__ flag,
                              void* __restrict__ out) {
  int t = threadIdx.x;
  int b = t >> 4, sub = t & 15;
  float a0 = 0.f, a1 = 0.f;
  #pragma unroll
  for (int j = 0; j < 16; ++j) {
    int e = sub * 16 + j;
    float p = pooled[b * 256 + e];
    a0 += p * bf2f(clsw[e * 2 + 0]);
    a1 += p * bf2f(clsw[e * 2 + 1]);
  }
  #pragma unroll
  for (int d = 1; d < 16; d <<= 1) {
    a0 += __shfl_xor(a0, d);
    a1 += __shfl_xor(a1, d);
  }
  if (sub == 0) {
    float o0 = a0 * (1.f / 2048.f) + bf2f(clsb[0]);
    float o1 = a1 * (1.f / 2048.f) + bf2f(clsb[1]);
    if (*flag) {
      ((float*)out)[b * 2 + 0] = o0; ((float*)out)[b * 2 + 1] = o1;
    } else {
      ((u16*)out)[b * 2 + 0] = f2bf(o0); ((u16*)out)[b * 2 + 1] = f2bf(o1);
    }
  }
}

extern "C" void kernel_launch(void* const* d_in, const int* in_sizes, int n_in,
                              void* d_out, int out_size, void* d_ws, size_t ws_size,
                              hipStream_t stream) {
  const int* tokens = (const int*)d_in[0];

  char* ws = (char*)d_ws;
  u16*   canon  = (u16*)(ws + 0);
  u16*   cwT    = (u16*)(ws + 1048576);
  u16*   l2T    = (u16*)(ws + 1310720);
  float* pooled = (float*)(ws + 1835008);
  int*   flag   = (int*)(ws + 1851392);
  u16*   x      = (u16*)(ws + 2097152);        // [32768][256] bf16
  u16*   buf    = (u16*)(ws + 18874368);       // h: [32768][512] bf16

  u16* c_attn = canon + 0;
  u16* c_cw   = canon + 128;
  u16* c_cb   = canon + 131200;
  u16* c_ft   = canon + 131712;
  u16* c_l1w  = canon + 131728;
  u16* c_l1b  = canon + 139920;
  u16* c_l2w  = canon + 140944;
  u16* c_l2b  = canon + 403088;
  u16* c_ln1g = canon + 403600;
  u16* c_ln1b = canon + 404112;
  u16* c_ln2g = canon + 404624;
  u16* c_ln2b = canon + 405136;
  u16* c_clsw = canon + 405648;
  u16* c_clsb = canon + 406160;

  sniff_kernel<<<1, 64, 0, stream>>>(d_in[1], flag);

  CanonArgs ca;
  for (int i = 0; i < 14; ++i) ca.p[i] = d_in[i + 2];
  canon_kernel<<<1587, 256, 0, stream>>>(ca, flag, canon);

  prep_kernel<<<1536, 256, 0, stream>>>(c_cw, c_l2w, cwT, l2T);
  embed_kernel<<<8192, 256, 0, stream>>>(tokens, d_in[1], flag, x);

  for (int l = 0; l < 2; ++l) {
    gemm_ln_kernel<256, true><<<512, 256, 0, stream>>>(x, cwT + l * 65536, c_cb + l * 256,
                                                       c_ln1g + l * 256, c_ln1b + l * 256,
                                                       c_attn + l * 64, x);
    h_kernel<<<1024, 256, 0, stream>>>(x, c_ft + l * 8, c_l1w + l * 4096, c_l1b + l * 512, buf);
    gemm_ln_kernel<512, false><<<512, 256, 0, stream>>>(buf, l2T + l * 131072, c_l2b + l * 256,
                                                        c_ln2g + l * 256, c_ln2b + l * 256,
                                                        nullptr, x);
  }

  hipMemsetAsync(pooled, 0, NBATCH * EDIM * sizeof(float), stream);
  pool_kernel<<<512, 256, 0, stream>>>(x, pooled);
  logits_kernel<<<1, 256, 0, stream>>>(pooled, c_clsw, c_clsb, flag, d_out);
}

// Round 5
// 309.179 us; speedup vs baseline: 1.3772x; 1.0820x over previous
//
#include <hip/hip_runtime.h>
#include <cstdint>
#include <cstddef>

#define SEQ   2048
#define EDIM  256
#define FFND  512
#define NBATCH 16

typedef unsigned short u16;
typedef __attribute__((ext_vector_type(8))) __bf16 bf16x8;
typedef __attribute__((ext_vector_type(4))) float f32x4;

__device__ __forceinline__ float bf2f(u16 u) {
  union { unsigned int w; float f; } v; v.w = ((unsigned int)u) << 16; return v.f;
}
__device__ __forceinline__ u16 f2bf(float f) {
  union { float f; unsigned int w; } v; v.f = f;
  unsigned int r = v.w + 0x7fffu + ((v.w >> 16) & 1u);
  return (u16)(r >> 16);
}
// hardware cos: v_cos_f32 takes revolutions; explicit fract keeps it in-range
__device__ __forceinline__ float fast_cos(float x) {
  float r = x * 0.15915494309189535f;
  r = r - floorf(r);
  return __builtin_amdgcn_cosf(r);
}
// XOR-swizzle of 16B-chunk index (chunk = row*8 + col8): col8 ^= row&7.
// Kills the 16-way bank conflict on fragment ds_read_b128 (row stride 128B).
__device__ __forceinline__ int swz(int chunk) {
  return (chunk & ~7) | ((chunk ^ (chunk >> 3)) & 7);
}

// -------- sniff: float inputs f32 (flag=1) or bf16 (flag=0) --------
__global__ void sniff_kernel(const void* embed, int* flag) {
  int t = threadIdx.x;
  const u16* p = (const u16*)embed;
  int c = 0;
  #pragma unroll
  for (int j = 0; j < 8; ++j) {
    u16 v = p[t * 8 + j];
    int e = (v >> 7) & 0xff;
    c += (e > 128) ? 1 : 0;
  }
  #pragma unroll
  for (int d = 1; d < 64; d <<= 1) c += __shfl_xor(c, d);
  if (t == 0) *flag = (c > 64) ? 1 : 0;
}

// -------- canonicalize all small float params to bf16 in ws --------
struct CanonArgs { const void* p[14]; };

__global__ void canon_kernel(CanonArgs a, const int* __restrict__ flag, u16* __restrict__ dst) {
  const int off[15] = {0, 128, 131200, 131712, 131728, 139920, 140944, 403088,
                       403600, 404112, 404624, 405136, 405648, 406160, 406162};
  int i = blockIdx.x * 256 + threadIdx.x;
  if (i >= 406162) return;
  int isf32 = *flag;
  int s = 0;
  #pragma unroll
  for (int k = 0; k < 13; ++k) s += (i >= off[k + 1]) ? 1 : 0;
  int j = i - off[s];
  u16 v = isf32 ? f2bf(((const float*)a.p[s])[j]) : ((const u16*)a.p[s])[j];
  dst[i] = v;
}

// ---------------- prep: transpose weights to [n][k] ----------------
__global__ void prep_kernel(const u16* __restrict__ cw, const u16* __restrict__ l2,
                            u16* __restrict__ cwT, u16* __restrict__ l2T) {
  int id = blockIdx.x * 256 + threadIdx.x;
  if (id < 2 * 256 * 256) {
    int l = id >> 16, rem = id & 65535;
    int n = rem >> 8, k = rem & 255;
    cwT[id] = cw[l * 65536 + k * 256 + n];
  } else {
    int j = id - 131072;
    if (j < 2 * 512 * 256) {
      int l = j >> 17, rem = j & 131071;
      int n = rem >> 9, k = rem & 511;
      l2T[j] = l2[l * 131072 + k * 256 + n];
    }
  }
}

// ---------------- embed + positional encoding -> x (bf16) ----------------
__global__ void embed_kernel(const int* __restrict__ tokens, const void* __restrict__ embed,
                             const int* __restrict__ flag, u16* __restrict__ x) {
  int t = threadIdx.x;
  int m = blockIdx.x * 4 + (t >> 6);
  int e0 = (t & 63) * 4;
  int tok = tokens[m];
  float ev[4];
  if (*flag) {
    float4 v = *reinterpret_cast<const float4*>((const float*)embed + (size_t)tok * EDIM + e0);
    ev[0] = v.x; ev[1] = v.y; ev[2] = v.z; ev[3] = v.w;
  } else {
    uint2 v = *reinterpret_cast<const uint2*>((const u16*)embed + (size_t)tok * EDIM + e0);
    ev[0] = bf2f((u16)(v.x & 0xffff)); ev[1] = bf2f((u16)(v.x >> 16));
    ev[2] = bf2f((u16)(v.y & 0xffff)); ev[3] = bf2f((u16)(v.y >> 16));
  }
  int s = m & (SEQ - 1);
  const float c0 = 9.210340371976184f / 128.f;  // ln(10000)/128
  const float inv2pi = 0.15915494309189535f;
  u16 o[4];
  #pragma unroll
  for (int j = 0; j < 4; ++j) {
    int e = e0 + j;
    int i = e >> 1;
    float revfreq = __expf(-(float)i * c0) * inv2pi;
    float rev = (float)s * revfreq;
    rev = rev - floorf(rev);
    float pe = (e & 1) ? __builtin_amdgcn_cosf(rev) : __builtin_amdgcn_sinf(rev);
    o[j] = f2bf(ev[j] + pe);
  }
  *reinterpret_cast<uint2*>(x + (size_t)m * EDIM + e0) = *reinterpret_cast<const uint2*>(o);
}

// ------- fused GEMM (A x BT[N=256,K]) + bias + residual + LN; FUSE: A=cos(x+theta) -------
template<int K, bool FUSE>
__launch_bounds__(256, 3)
__global__ void gemm_ln_kernel(const u16* A, const u16* __restrict__ BT,
                               const u16* __restrict__ bias, const u16* __restrict__ gamma,
                               const u16* __restrict__ beta, const u16* __restrict__ theta,
                               u16* x) {
  __shared__ union SU {
    struct { u16 At[64 * 64]; u16 Bt[256 * 64]; } t;  // 8KB + 32KB (swizzled)
    u16 epi[64 * 256];                                 // 32KB epilogue tile
  } sh;
  __shared__ float2 sstat[64][5];
  __shared__ float2 sms[64];

  const int tid = threadIdx.x;
  const int wave = tid >> 6, lane = tid & 63;
  const int m0 = blockIdx.x * 64;
  const int fr = lane & 15, fq = lane >> 4;

  float th[8];
  if (FUSE) {
    #pragma unroll
    for (int j = 0; j < 8; ++j) th[j] = bf2f(theta[(tid & 7) * 8 + j]);  // k&63 slice
  }

  f32x4 acc[4][4];
  #pragma unroll
  for (int i = 0; i < 4; ++i)
    #pragma unroll
    for (int j = 0; j < 4; ++j)
      acc[i][j] = {0.f, 0.f, 0.f, 0.f};

  for (int k0 = 0; k0 < K; k0 += 64) {
    const u16* asrc = A + (size_t)m0 * K + k0;
    const u16* bsrc = BT + k0;
    uint4 ga[2], gb[8];
    #pragma unroll
    for (int it = 0; it < 2; ++it) {
      int chunk = tid + it * 256;
      ga[it] = *reinterpret_cast<const uint4*>(asrc + (size_t)(chunk >> 3) * K + (chunk & 7) * 8);
    }
    #pragma unroll
    for (int it = 0; it < 8; ++it) {
      int chunk = tid + it * 256;
      gb[it] = *reinterpret_cast<const uint4*>(bsrc + (size_t)(chunk >> 3) * K + (chunk & 7) * 8);
    }
    if (FUSE) {
      #pragma unroll
      for (int it = 0; it < 2; ++it) {
        u16* gp = reinterpret_cast<u16*>(&ga[it]);
        #pragma unroll
        for (int j = 0; j < 8; ++j)
          gp[j] = f2bf(fast_cos(bf2f(gp[j]) + th[j]));
      }
    }
    #pragma unroll
    for (int it = 0; it < 2; ++it)
      *reinterpret_cast<uint4*>(sh.t.At + swz(tid + it * 256) * 8) = ga[it];
    #pragma unroll
    for (int it = 0; it < 8; ++it)
      *reinterpret_cast<uint4*>(sh.t.Bt + swz(tid + it * 256) * 8) = gb[it];
    __syncthreads();

    const bf16x8* Ap = reinterpret_cast<const bf16x8*>(sh.t.At);
    const bf16x8* Bp = reinterpret_cast<const bf16x8*>(sh.t.Bt);
    #pragma unroll
    for (int ks = 0; ks < 2; ++ks) {
      bf16x8 af[4], bfv[4];
      #pragma unroll
      for (int mi = 0; mi < 4; ++mi)
        af[mi] = Ap[swz((mi * 16 + fr) * 8 + ks * 4 + fq)];
      #pragma unroll
      for (int ni = 0; ni < 4; ++ni)
        bfv[ni] = Bp[swz((wave * 64 + ni * 16 + fr) * 8 + ks * 4 + fq)];
      #pragma unroll
      for (int mi = 0; mi < 4; ++mi)
        #pragma unroll
        for (int ni = 0; ni < 4; ++ni)
          acc[mi][ni] = __builtin_amdgcn_mfma_f32_16x16x32_bf16(af[mi], bfv[ni], acc[mi][ni], 0, 0, 0);
    }
    __syncthreads();
  }

  // ---- epilogue (C/D: row=mi*16+fq*4+rg, col=wave*64+ni*16+fr) ----
  // stage residual tile [64][256] into LDS, coalesced
  const u16* xtile = x + (size_t)m0 * EDIM;
  {
    uint4 rv[8];
    #pragma unroll
    for (int it = 0; it < 8; ++it)
      rv[it] = *reinterpret_cast<const uint4*>(xtile + (size_t)(tid + it * 256) * 8);
    #pragma unroll
    for (int it = 0; it < 8; ++it)
      *reinterpret_cast<uint4*>(sh.epi + (tid + it * 256) * 8) = rv[it];
  }
  __syncthreads();

  int cols[4];
  float bcol[4];
  #pragma unroll
  for (int ni = 0; ni < 4; ++ni) {
    cols[ni] = wave * 64 + ni * 16 + fr;
    bcol[ni] = bf2f(bias[cols[ni]]);
  }
  #pragma unroll
  for (int mi = 0; mi < 4; ++mi)
    #pragma unroll
    for (int rg = 0; rg < 4; ++rg) {
      int lrow = mi * 16 + fq * 4 + rg;
      #pragma unroll
      for (int ni = 0; ni < 4; ++ni)
        acc[mi][ni][rg] += bf2f(sh.epi[lrow * 256 + cols[ni]]) + bcol[ni];
    }
  // per-row LN stats: partials over 4 cols, butterfly over fr lanes, cross-wave via LDS
  float sr[4][4], sq[4][4];
  #pragma unroll
  for (int mi = 0; mi < 4; ++mi)
    #pragma unroll
    for (int rg = 0; rg < 4; ++rg) {
      float a = 0.f, b = 0.f;
      #pragma unroll
      for (int ni = 0; ni < 4; ++ni) {
        float t2 = acc[mi][ni][rg];
        a += t2; b += t2 * t2;
      }
      sr[mi][rg] = a; sq[mi][rg] = b;
    }
  #pragma unroll
  for (int d = 1; d < 16; d <<= 1)
    #pragma unroll
    for (int mi = 0; mi < 4; ++mi)
      #pragma unroll
      for (int rg = 0; rg < 4; ++rg) {
        sr[mi][rg] += __shfl_xor(sr[mi][rg], d);
        sq[mi][rg] += __shfl_xor(sq[mi][rg], d);
      }
  if (fr == 0) {
    #pragma unroll
    for (int mi = 0; mi < 4; ++mi)
      #pragma unroll
      for (int rg = 0; rg < 4; ++rg)
        sstat[mi * 16 + fq * 4 + rg][wave] = float2{sr[mi][rg], sq[mi][rg]};
  }
  __syncthreads();
  if (tid < 64) {
    float s = 0.f, s2 = 0.f;
    #pragma unroll
    for (int w = 0; w < 4; ++w) {
      float2 p = sstat[tid][w];
      s += p.x; s2 += p.y;
    }
    float mean = s * (1.f / 256.f);
    float var = fmaxf(s2 * (1.f / 256.f) - mean * mean, 0.f);
    sms[tid] = float2{mean, rsqrtf(var + 1e-5f)};
  }
  __syncthreads();
  float gcol[4], btcol[4];
  #pragma unroll
  for (int ni = 0; ni < 4; ++ni) {
    gcol[ni] = bf2f(gamma[cols[ni]]);
    btcol[ni] = bf2f(beta[cols[ni]]);
  }
  #pragma unroll
  for (int mi = 0; mi < 4; ++mi)
    #pragma unroll
    for (int rg = 0; rg < 4; ++rg) {
      int lrow = mi * 16 + fq * 4 + rg;
      float2 ms = sms[lrow];
      #pragma unroll
      for (int ni = 0; ni < 4; ++ni) {
        float o = (acc[mi][ni][rg] - ms.x) * ms.y * gcol[ni] + btcol[ni];
        sh.epi[lrow * 256 + cols[ni]] = f2bf(o);
      }
    }
  __syncthreads();
  // coalesced write-back
  {
    uint4 rv[8];
    #pragma unroll
    for (int it = 0; it < 8; ++it)
      rv[it] = *reinterpret_cast<const uint4*>(sh.epi + (tid + it * 256) * 8);
    u16* xo = x + (size_t)m0 * EDIM;
    #pragma unroll
    for (int it = 0; it < 8; ++it)
      *reinterpret_cast<uint4*>(xo + (size_t)(tid + it * 256) * 8) = rv[it];
  }
}

// ------- h = relu(q @ lin1_w + b1); q computed ONCE per row into LDS -------
__global__ void h_kernel(const u16* __restrict__ x, const u16* __restrict__ ffn_theta,
                         const u16* __restrict__ w1, const u16* __restrict__ b1,
                         u16* __restrict__ h) {
  __shared__ float qs[32][8];   // 1 KB
  const int tid = threadIdx.x;
  const int m0 = blockIdx.x * 32;
  {
    int r = tid >> 3, n = tid & 7;
    float xv = bf2f(x[(size_t)(m0 + r) * EDIM + n]);
    qs[r][n] = fast_cos(xv) * fast_cos(bf2f(ffn_theta[n]));
  }
  __syncthreads();
  const int c0 = (tid & 63) * 8, rg = tid >> 6;
  float wf[8][8];
  #pragma unroll
  for (int n = 0; n < 8; ++n) {
    uint4 wv = *reinterpret_cast<const uint4*>(w1 + n * FFND + c0);
    const u16* wp = reinterpret_cast<const u16*>(&wv);
    #pragma unroll
    for (int j = 0; j < 8; ++j) wf[n][j] = bf2f(wp[j]);
  }
  float bv[8];
  {
    uint4 bvv = *reinterpret_cast<const uint4*>(b1 + c0);
    const u16* bp = reinterpret_cast<const u16*>(&bvv);
    #pragma unroll
    for (int j = 0; j < 8; ++j) bv[j] = bf2f(bp[j]);
  }
  for (int r = rg; r < 32; r += 4) {
    float4 qa = *reinterpret_cast<const float4*>(&qs[r][0]);
    float4 qb = *reinterpret_cast<const float4*>(&qs[r][4]);
    float qv[8] = {qa.x, qa.y, qa.z, qa.w, qb.x, qb.y, qb.z, qb.w};
    float acc[8];
    #pragma unroll
    for (int j = 0; j < 8; ++j) acc[j] = bv[j];
    #pragma unroll
    for (int n = 0; n < 8; ++n)
      #pragma unroll
      for (int j = 0; j < 8; ++j)
        acc[j] += qv[n] * wf[n][j];
    u16 o[8];
    #pragma unroll
    for (int j = 0; j < 8; ++j) o[j] = f2bf(fmaxf(acc[j], 0.f));
    *reinterpret_cast<uint4*>(h + (size_t)(m0 + r) * FFND + c0) = *reinterpret_cast<const uint4*>(o);
  }
}

// ---------------- mean pool over S (pooled holds SUM) ----------------
__global__ void pool_kernel(const u16* __restrict__ x, float* __restrict__ pooled) {
  int b = blockIdx.x >> 5, rq = blockIdx.x & 31;
  int t = threadIdx.x;
  int c4 = (t & 63) * 4, rg = t >> 6;
  const u16* base = x + ((size_t)b * SEQ + rq * 64 + rg) * EDIM + c4;
  float s0 = 0.f, s1 = 0.f, s2 = 0.f, s3 = 0.f;
  #pragma unroll 4
  for (int j = 0; j < 16; ++j) {
    uint2 v = *reinterpret_cast<const uint2*>(base + (size_t)j * 4 * EDIM);
    s0 += bf2f((u16)(v.x & 0xffff)); s1 += bf2f((u16)(v.x >> 16));
    s2 += bf2f((u16)(v.y & 0xffff)); s3 += bf2f((u16)(v.y >> 16));
  }
  float* p = pooled + b * EDIM + c4;
  atomicAdd(p + 0, s0); atomicAdd(p + 1, s1);
  atomicAdd(p + 2, s2); atomicAdd(p + 3, s3);
}

__global__ void logits_kernel(const float* __restrict__ pooled, const u16* __restrict__ clsw,
                              const u16* __restrict__ clsb, const int* __restrict__ flag,
                              void* __restrict__ out) {
  int t = threadIdx.x;
  int b = t >> 4, sub = t & 15;
  float a0 = 0.f, a1 = 0.f;
  #pragma unroll
  for (int j = 0; j < 16; ++j) {
    int e = sub * 16 + j;
    float p = pooled[b * 256 + e];
    a0 += p * bf2f(clsw[e * 2 + 0]);
    a1 += p * bf2f(clsw[e * 2 + 1]);
  }
  #pragma unroll
  for (int d = 1; d < 16; d <<= 1) {
    a0 += __shfl_xor(a0, d);
    a1 += __shfl_xor(a1, d);
  }
  if (sub == 0) {
    float o0 = a0 * (1.f / 2048.f) + bf2f(clsb[0]);
    float o1 = a1 * (1.f / 2048.f) + bf2f(clsb[1]);
    if (*flag) {
      ((float*)out)[b * 2 + 0] = o0; ((float*)out)[b * 2 + 1] = o1;
    } else {
      ((u16*)out)[b * 2 + 0] = f2bf(o0); ((u16*)out)[b * 2 + 1] = f2bf(o1);
    }
  }
}

extern "C" void kernel_launch(void* const* d_in, const int* in_sizes, int n_in,
                              void* d_out, int out_size, void* d_ws, size_t ws_size,
                              hipStream_t stream) {
  const int* tokens = (const int*)d_in[0];

  char* ws = (char*)d_ws;
  u16*   canon  = (u16*)(ws + 0);
  u16*   cwT    = (u16*)(ws + 1048576);
  u16*   l2T    = (u16*)(ws + 1310720);
  float* pooled = (float*)(ws + 1835008);
  int*   flag   = (int*)(ws + 1851392);
  u16*   x      = (u16*)(ws + 2097152);        // [32768][256] bf16
  u16*   buf    = (u16*)(ws + 18874368);       // h: [32768][512] bf16

  u16* c_attn = canon + 0;
  u16* c_cw   = canon + 128;
  u16* c_cb   = canon + 131200;
  u16* c_ft   = canon + 131712;
  u16* c_l1w  = canon + 131728;
  u16* c_l1b  = canon + 139920;
  u16* c_l2w  = canon + 140944;
  u16* c_l2b  = canon + 403088;
  u16* c_ln1g = canon + 403600;
  u16* c_ln1b = canon + 404112;
  u16* c_ln2g = canon + 404624;
  u16* c_ln2b = canon + 405136;
  u16* c_clsw = canon + 405648;
  u16* c_clsb = canon + 406160;

  sniff_kernel<<<1, 64, 0, stream>>>(d_in[1], flag);

  CanonArgs ca;
  for (int i = 0; i < 14; ++i) ca.p[i] = d_in[i + 2];
  canon_kernel<<<1587, 256, 0, stream>>>(ca, flag, canon);

  prep_kernel<<<1536, 256, 0, stream>>>(c_cw, c_l2w, cwT, l2T);
  embed_kernel<<<8192, 256, 0, stream>>>(tokens, d_in[1], flag, x);

  for (int l = 0; l < 2; ++l) {
    gemm_ln_kernel<256, true><<<512, 256, 0, stream>>>(x, cwT + l * 65536, c_cb + l * 256,
                                                       c_ln1g + l * 256, c_ln1b + l * 256,
                                                       c_attn + l * 64, x);
    h_kernel<<<1024, 256, 0, stream>>>(x, c_ft + l * 8, c_l1w + l * 4096, c_l1b + l * 512, buf);
    gemm_ln_kernel<512, false><<<512, 256, 0, stream>>>(buf, l2T + l * 131072, c_l2b + l * 256,
                                                        c_ln2g + l * 256, c_ln2b + l * 256,
                                                        nullptr, x);
  }

  hipMemsetAsync(pooled, 0, NBATCH * EDIM * sizeof(float), stream);
  pool_kernel<<<512, 256, 0, stream>>>(x, pooled);
  logits_kernel<<<1, 256, 0, stream>>>(pooled, c_clsw, c_clsb, flag, d_out);
}

// Round 6
// 297.772 us; speedup vs baseline: 1.4299x; 1.0383x over previous
//
#include <hip/hip_runtime.h>
#include <cstdint>
#include <cstddef>

#define SEQ   2048
#define EDIM  256
#define FFND  512
#define NBATCH 16

typedef unsigned short u16;
typedef __attribute__((ext_vector_type(8))) __bf16 bf16x8;
typedef __attribute__((ext_vector_type(4))) float f32x4;

__device__ __forceinline__ float bf2f(u16 u) {
  union { unsigned int w; float f; } v; v.w = ((unsigned int)u) << 16; return v.f;
}
__device__ __forceinline__ u16 f2bf(float f) {
  union { float f; unsigned int w; } v; v.f = f;
  unsigned int r = v.w + 0x7fffu + ((v.w >> 16) & 1u);
  return (u16)(r >> 16);
}
// hardware cos: v_cos_f32 takes revolutions; explicit fract keeps it in-range
__device__ __forceinline__ float fast_cos(float x) {
  float r = x * 0.15915494309189535f;
  r = r - floorf(r);
  return __builtin_amdgcn_cosf(r);
}
__device__ __forceinline__ void unpack8(bf16x8 v, float* o) {
  const u16* p = (const u16*)&v;
  #pragma unroll
  for (int j = 0; j < 8; ++j) o[j] = bf2f(p[j]);
}

// -------- sniff: float inputs f32 (flag=1) or bf16 (flag=0) --------
__global__ void sniff_kernel(const void* embed, int* flag) {
  int t = threadIdx.x;
  const u16* p = (const u16*)embed;
  int c = 0;
  #pragma unroll
  for (int j = 0; j < 8; ++j) {
    u16 v = p[t * 8 + j];
    int e = (v >> 7) & 0xff;
    c += (e > 128) ? 1 : 0;
  }
  #pragma unroll
  for (int d = 1; d < 64; d <<= 1) c += __shfl_xor(c, d);
  if (t == 0) *flag = (c > 64) ? 1 : 0;
}

// -------- canonicalize all small float params to bf16 in ws --------
struct CanonArgs { const void* p[14]; };

__global__ void canon_kernel(CanonArgs a, const int* __restrict__ flag, u16* __restrict__ dst) {
  const int off[15] = {0, 128, 131200, 131712, 131728, 139920, 140944, 403088,
                       403600, 404112, 404624, 405136, 405648, 406160, 406162};
  int i = blockIdx.x * 256 + threadIdx.x;
  if (i >= 406162) return;
  int isf32 = *flag;
  int s = 0;
  #pragma unroll
  for (int k = 0; k < 13; ++k) s += (i >= off[k + 1]) ? 1 : 0;
  int j = i - off[s];
  u16 v = isf32 ? f2bf(((const float*)a.p[s])[j]) : ((const u16*)a.p[s])[j];
  dst[i] = v;
}

// ---- prep: weights to staging layout [K/8][256][8] (k-chunked, n-major, k-inner) ----
__global__ void prep_kernel(const u16* __restrict__ cw, const u16* __restrict__ l2,
                            u16* __restrict__ cwT, u16* __restrict__ l2T) {
  int id = blockIdx.x * 256 + threadIdx.x;
  if (id < 2 * 256 * 256) {
    int l = id >> 16, rem = id & 65535;
    int kc = rem >> 11, n = (rem >> 3) & 255, kj = rem & 7;
    cwT[id] = cw[l * 65536 + (kc * 8 + kj) * 256 + n];
  } else {
    int j = id - 131072;
    if (j < 2 * 512 * 256) {
      int l = j >> 17, rem = j & 131071;
      int kc = rem >> 11, n = (rem >> 3) & 255, kj = rem & 7;
      l2T[j] = l2[l * 131072 + (kc * 8 + kj) * 256 + n];
    }
  }
}

// ---------------- embed + positional encoding -> x (bf16) ----------------
__global__ void embed_kernel(const int* __restrict__ tokens, const void* __restrict__ embed,
                             const int* __restrict__ flag, u16* __restrict__ x) {
  int t = threadIdx.x;
  int m = blockIdx.x * 4 + (t >> 6);
  int e0 = (t & 63) * 4;
  int tok = tokens[m];
  float ev[4];
  if (*flag) {
    float4 v = *reinterpret_cast<const float4*>((const float*)embed + (size_t)tok * EDIM + e0);
    ev[0] = v.x; ev[1] = v.y; ev[2] = v.z; ev[3] = v.w;
  } else {
    uint2 v = *reinterpret_cast<const uint2*>((const u16*)embed + (size_t)tok * EDIM + e0);
    ev[0] = bf2f((u16)(v.x & 0xffff)); ev[1] = bf2f((u16)(v.x >> 16));
    ev[2] = bf2f((u16)(v.y & 0xffff)); ev[3] = bf2f((u16)(v.y >> 16));
  }
  int s = m & (SEQ - 1);
  const float c0 = 9.210340371976184f / 128.f;  // ln(10000)/128
  const float inv2pi = 0.15915494309189535f;
  u16 o[4];
  #pragma unroll
  for (int j = 0; j < 4; ++j) {
    int e = e0 + j;
    int i = e >> 1;
    float revfreq = __expf(-(float)i * c0) * inv2pi;
    float rev = (float)s * revfreq;
    rev = rev - floorf(rev);
    float pe = (e & 1) ? __builtin_amdgcn_cosf(rev) : __builtin_amdgcn_sinf(rev);
    o[j] = f2bf(ev[j] + pe);
  }
  *reinterpret_cast<uint2*>(x + (size_t)m * EDIM + e0) = *reinterpret_cast<const uint2*>(o);
}

// ====== fused GEMM + bias + residual + LN ======
// A-operand: FUSEH=false -> A = cos(x + theta) computed in staging (attn GEMM, K=256)
//            FUSEH=true  -> A = h = relu(q @ W1 + b1) computed in staging (ffn GEMM, K=512)
// B-operand: Bp in prepped [K/8][256][8] layout, staged via global_load_lds width-16.
// LDS layouts: B [kc][n] chunks (conflict-free frag reads), A [kc][m^kc] (XOR, conflict-free).
template<int K, bool FUSEH>
__launch_bounds__(256, 3)
__global__ void gemm_ln_kernel(const u16* A, const u16* __restrict__ Bp,
                               const u16* __restrict__ bias, const u16* __restrict__ gamma,
                               const u16* __restrict__ beta, const u16* __restrict__ theta,
                               const u16* __restrict__ w1, const u16* __restrict__ b1,
                               u16* x) {
  __shared__ union SU {
    struct { u16 Bt[256 * 64]; u16 At[64 * 64]; } t;  // 32KB + 8KB
    u16 epi[64 * 256];                                 // 32KB epilogue tile
  } sh;
  __shared__ u16 qsL[64 * 8];     // 1KB  (FUSEH: q per row, bf16)
  __shared__ u16 w1L[8 * 512];    // 8KB  (FUSEH: W1)
  __shared__ u16 b1L[512];        // 1KB  (FUSEH: b1)
  __shared__ float2 sstat[64][5];
  __shared__ float2 sms[64];

  const int tid = threadIdx.x;
  const int wave = tid >> 6, lane = tid & 63;
  const int m0 = blockIdx.x * 64;
  const int fr = lane & 15, fq = lane >> 4;

  float th[8];
  if (!FUSEH) {
    #pragma unroll
    for (int j = 0; j < 8; ++j) th[j] = bf2f(theta[(tid & 7) * 8 + j]);
  } else {
    // stage W1 [8][512] and b1 into LDS (broadcast-read later = conflict-free)
    #pragma unroll
    for (int it = 0; it < 2; ++it)
      reinterpret_cast<uint4*>(w1L)[tid + it * 256] =
          reinterpret_cast<const uint4*>(w1)[tid + it * 256];
    if (tid < 64)
      reinterpret_cast<uint4*>(b1L)[tid] = reinterpret_cast<const uint4*>(b1)[tid];
    // q[r][n] = cos(x[r][n]) * cos(theta[n]), bf16, for the block's 64 rows
    int r = tid >> 3, n = tid & 7;
    float cth = fast_cos(bf2f(theta[n]));
    qsL[r * 8 + n] = f2bf(fast_cos(bf2f(A[(size_t)(m0 + r) * EDIM + n])) * cth);
    qsL[(r + 32) * 8 + n] = f2bf(fast_cos(bf2f(A[(size_t)(m0 + r + 32) * EDIM + n])) * cth);
    __syncthreads();
  }

  f32x4 acc[4][4];
  #pragma unroll
  for (int i = 0; i < 4; ++i)
    #pragma unroll
    for (int j = 0; j < 4; ++j)
      acc[i][j] = {0.f, 0.f, 0.f, 0.f};

  for (int k0 = 0; k0 < K; k0 += 64) {
    // --- B: async direct-to-LDS, 16B/lane, dest = uniform base + lane*16 ---
    const u16* bsrc = Bp + (size_t)(k0 >> 3) * 2048;
    #pragma unroll
    for (int it = 0; it < 8; ++it) {
      int c = tid + it * 256;
      __builtin_amdgcn_global_load_lds(
          (const __attribute__((address_space(1))) void*)(bsrc + (size_t)c * 8),
          (__attribute__((address_space(3))) void*)(sh.t.Bt + c * 8), 16, 0, 0);
    }
    // --- A: computed in registers, ds_write to [kc][m^kc] ---
    if (!FUSEH) {
      #pragma unroll
      for (int it = 0; it < 2; ++it) {
        int c = tid + it * 256;
        int r = c >> 3, f8 = c & 7;
        uint4 g = *reinterpret_cast<const uint4*>(A + (size_t)(m0 + r) * 256 + k0 + f8 * 8);
        u16* gp = reinterpret_cast<u16*>(&g);
        #pragma unroll
        for (int j = 0; j < 8; ++j)
          gp[j] = f2bf(fast_cos(bf2f(gp[j]) + th[j]));
        reinterpret_cast<uint4*>(sh.t.At)[f8 * 64 + (r ^ f8)] = g;
      }
    } else {
      #pragma unroll
      for (int it = 0; it < 2; ++it) {
        int c = tid + it * 256;
        int kc = c >> 6, r = c & 63;
        int cc = (k0 >> 3) + kc;  // global col-chunk of W1/b1 (wave-uniform)
        float qf[8], hv[8];
        unpack8(reinterpret_cast<const bf16x8*>(qsL)[r], qf);
        unpack8(reinterpret_cast<const bf16x8*>(b1L)[cc], hv);
        #pragma unroll
        for (int n = 0; n < 8; ++n) {
          float wf[8];
          unpack8(reinterpret_cast<const bf16x8*>(w1L)[n * 64 + cc], wf);
          #pragma unroll
          for (int j = 0; j < 8; ++j) hv[j] += qf[n] * wf[j];
        }
        uint4 g;
        u16* gp = reinterpret_cast<u16*>(&g);
        #pragma unroll
        for (int j = 0; j < 8; ++j) gp[j] = f2bf(fmaxf(hv[j], 0.f));
        reinterpret_cast<uint4*>(sh.t.At)[kc * 64 + (r ^ kc)] = g;
      }
    }
    __syncthreads();  // drains vmcnt (global_load_lds) + lgkm (ds_write)

    const bf16x8* Av = reinterpret_cast<const bf16x8*>(sh.t.At);
    const bf16x8* Bv = reinterpret_cast<const bf16x8*>(sh.t.Bt);
    #pragma unroll
    for (int ks = 0; ks < 2; ++ks) {
      const int kc = ks * 4 + fq;
      bf16x8 af[4], bfv[4];
      #pragma unroll
      for (int mi = 0; mi < 4; ++mi)
        af[mi] = Av[kc * 64 + ((mi * 16 + fr) ^ kc)];
      #pragma unroll
      for (int ni = 0; ni < 4; ++ni)
        bfv[ni] = Bv[kc * 256 + wave * 64 + ni * 16 + fr];
      #pragma unroll
      for (int mi = 0; mi < 4; ++mi)
        #pragma unroll
        for (int ni = 0; ni < 4; ++ni)
          acc[mi][ni] = __builtin_amdgcn_mfma_f32_16x16x32_bf16(af[mi], bfv[ni], acc[mi][ni], 0, 0, 0);
    }
    __syncthreads();
  }

  // ---- epilogue (C/D: row=mi*16+fq*4+rg, col=wave*64+ni*16+fr) ----
  const u16* xtile = x + (size_t)m0 * EDIM;
  {
    uint4 rv[8];
    #pragma unroll
    for (int it = 0; it < 8; ++it)
      rv[it] = *reinterpret_cast<const uint4*>(xtile + (size_t)(tid + it * 256) * 8);
    #pragma unroll
    for (int it = 0; it < 8; ++it)
      *reinterpret_cast<uint4*>(sh.epi + (tid + it * 256) * 8) = rv[it];
  }
  __syncthreads();

  int cols[4];
  float bcol[4];
  #pragma unroll
  for (int ni = 0; ni < 4; ++ni) {
    cols[ni] = wave * 64 + ni * 16 + fr;
    bcol[ni] = bf2f(bias[cols[ni]]);
  }
  #pragma unroll
  for (int mi = 0; mi < 4; ++mi)
    #pragma unroll
    for (int rg = 0; rg < 4; ++rg) {
      int lrow = mi * 16 + fq * 4 + rg;
      #pragma unroll
      for (int ni = 0; ni < 4; ++ni)
        acc[mi][ni][rg] += bf2f(sh.epi[lrow * 256 + cols[ni]]) + bcol[ni];
    }
  float sr[4][4], sq[4][4];
  #pragma unroll
  for (int mi = 0; mi < 4; ++mi)
    #pragma unroll
    for (int rg = 0; rg < 4; ++rg) {
      float a = 0.f, b = 0.f;
      #pragma unroll
      for (int ni = 0; ni < 4; ++ni) {
        float t2 = acc[mi][ni][rg];
        a += t2; b += t2 * t2;
      }
      sr[mi][rg] = a; sq[mi][rg] = b;
    }
  #pragma unroll
  for (int d = 1; d < 16; d <<= 1)
    #pragma unroll
    for (int mi = 0; mi < 4; ++mi)
      #pragma unroll
      for (int rg = 0; rg < 4; ++rg) {
        sr[mi][rg] += __shfl_xor(sr[mi][rg], d);
        sq[mi][rg] += __shfl_xor(sq[mi][rg], d);
      }
  if (fr == 0) {
    #pragma unroll
    for (int mi = 0; mi < 4; ++mi)
      #pragma unroll
      for (int rg = 0; rg < 4; ++rg)
        sstat[mi * 16 + fq * 4 + rg][wave] = float2{sr[mi][rg], sq[mi][rg]};
  }
  __syncthreads();
  if (tid < 64) {
    float s = 0.f, s2 = 0.f;
    #pragma unroll
    for (int w = 0; w < 4; ++w) {
      float2 p = sstat[tid][w];
      s += p.x; s2 += p.y;
    }
    float mean = s * (1.f / 256.f);
    float var = fmaxf(s2 * (1.f / 256.f) - mean * mean, 0.f);
    sms[tid] = float2{mean, rsqrtf(var + 1e-5f)};
  }
  __syncthreads();
  float gcol[4], btcol[4];
  #pragma unroll
  for (int ni = 0; ni < 4; ++ni) {
    gcol[ni] = bf2f(gamma[cols[ni]]);
    btcol[ni] = bf2f(beta[cols[ni]]);
  }
  #pragma unroll
  for (int mi = 0; mi < 4; ++mi)
    #pragma unroll
    for (int rg = 0; rg < 4; ++rg) {
      int lrow = mi * 16 + fq * 4 + rg;
      float2 ms = sms[lrow];
      #pragma unroll
      for (int ni = 0; ni < 4; ++ni) {
        float o = (acc[mi][ni][rg] - ms.x) * ms.y * gcol[ni] + btcol[ni];
        sh.epi[lrow * 256 + cols[ni]] = f2bf(o);
      }
    }
  __syncthreads();
  {
    uint4 rv[8];
    #pragma unroll
    for (int it = 0; it < 8; ++it)
      rv[it] = *reinterpret_cast<const uint4*>(sh.epi + (tid + it * 256) * 8);
    u16* xo = x + (size_t)m0 * EDIM;
    #pragma unroll
    for (int it = 0; it < 8; ++it)
      *reinterpret_cast<uint4*>(xo + (size_t)(tid + it * 256) * 8) = rv[it];
  }
}

// ---------------- mean pool over S (pooled holds SUM) ----------------
__global__ void pool_kernel(const u16* __restrict__ x, float* __restrict__ pooled) {
  int b = blockIdx.x >> 5, rq = blockIdx.x & 31;
  int t = threadIdx.x;
  int c4 = (t & 63) * 4, rg = t >> 6;
  const u16* base = x + ((size_t)b * SEQ + rq * 64 + rg) * EDIM + c4;
  float s0 = 0.f, s1 = 0.f, s2 = 0.f, s3 = 0.f;
  #pragma unroll 4
  for (int j = 0; j < 16; ++j) {
    uint2 v = *reinterpret_cast<const uint2*>(base + (size_t)j * 4 * EDIM);
    s0 += bf2f((u16)(v.x & 0xffff)); s1 += bf2f((u16)(v.x >> 16));
    s2 += bf2f((u16)(v.y & 0xffff)); s3 += bf2f((u16)(v.y >> 16));
  }
  float* p = pooled + b * EDIM + c4;
  atomicAdd(p + 0, s0); atomicAdd(p + 1, s1);
  atomicAdd(p + 2, s2); atomicAdd(p + 3, s3);
}

__global__ void logits_kernel(const float* __restrict__ pooled, const u16* __restrict__ clsw,
                              const u16* __restrict__ clsb, const int* __restrict__ flag,
                              void* __restrict__ out) {
  int t = threadIdx.x;
  int b = t >> 4, sub = t & 15;
  float a0 = 0.f, a1 = 0.f;
  #pragma unroll
  for (int j = 0; j < 16; ++j) {
    int e = sub * 16 + j;
    float p = pooled[b * 256 + e];
    a0 += p * bf2f(clsw[e * 2 + 0]);
    a1 += p * bf2f(clsw[e * 2 + 1]);
  }
  #pragma unroll
  for (int d = 1; d < 16; d <<= 1) {
    a0 += __shfl_xor(a0, d);
    a1 += __shfl_xor(a1, d);
  }
  if (sub == 0) {
    float o0 = a0 * (1.f / 2048.f) + bf2f(clsb[0]);
    float o1 = a1 * (1.f / 2048.f) + bf2f(clsb[1]);
    if (*flag) {
      ((float*)out)[b * 2 + 0] = o0; ((float*)out)[b * 2 + 1] = o1;
    } else {
      ((u16*)out)[b * 2 + 0] = f2bf(o0); ((u16*)out)[b * 2 + 1] = f2bf(o1);
    }
  }
}

extern "C" void kernel_launch(void* const* d_in, const int* in_sizes, int n_in,
                              void* d_out, int out_size, void* d_ws, size_t ws_size,
                              hipStream_t stream) {
  const int* tokens = (const int*)d_in[0];

  char* ws = (char*)d_ws;
  u16*   canon  = (u16*)(ws + 0);
  u16*   cwT    = (u16*)(ws + 1048576);
  u16*   l2T    = (u16*)(ws + 1310720);
  float* pooled = (float*)(ws + 1835008);
  int*   flag   = (int*)(ws + 1851392);
  u16*   x      = (u16*)(ws + 2097152);        // [32768][256] bf16

  u16* c_attn = canon + 0;
  u16* c_cw   = canon + 128;
  u16* c_cb   = canon + 131200;
  u16* c_ft   = canon + 131712;
  u16* c_l1w  = canon + 131728;
  u16* c_l1b  = canon + 139920;
  u16* c_l2w  = canon + 140944;
  u16* c_l2b  = canon + 403088;
  u16* c_ln1g = canon + 403600;
  u16* c_ln1b = canon + 404112;
  u16* c_ln2g = canon + 404624;
  u16* c_ln2b = canon + 405136;
  u16* c_clsw = canon + 405648;
  u16* c_clsb = canon + 406160;

  sniff_kernel<<<1, 64, 0, stream>>>(d_in[1], flag);

  CanonArgs ca;
  for (int i = 0; i < 14; ++i) ca.p[i] = d_in[i + 2];
  canon_kernel<<<1587, 256, 0, stream>>>(ca, flag, canon);

  prep_kernel<<<1536, 256, 0, stream>>>(c_cw, c_l2w, cwT, l2T);
  embed_kernel<<<8192, 256, 0, stream>>>(tokens, d_in[1], flag, x);

  for (int l = 0; l < 2; ++l) {
    gemm_ln_kernel<256, false><<<512, 256, 0, stream>>>(
        x, cwT + l * 65536, c_cb + l * 256, c_ln1g + l * 256, c_ln1b + l * 256,
        c_attn + l * 64, nullptr, nullptr, x);
    gemm_ln_kernel<512, true><<<512, 256, 0, stream>>>(
        x, l2T + l * 131072, c_l2b + l * 256, c_ln2g + l * 256, c_ln2b + l * 256,
        c_ft + l * 8, c_l1w + l * 4096, c_l1b + l * 512, x);
  }

  hipMemsetAsync(pooled, 0, NBATCH * EDIM * sizeof(float), stream);
  pool_kernel<<<512, 256, 0, stream>>>(x, pooled);
  logits_kernel<<<1, 256, 0, stream>>>(pooled, c_clsw, c_clsb, flag, d_out);
}

// Round 8
// 215.403 us; speedup vs baseline: 1.9767x; 1.3824x over previous
//
#include <hip/hip_runtime.h>
#include <cstdint>
#include <cstddef>

#define SEQ   2048
#define EDIM  256
#define FFND  512
#define NBATCH 16
#define XLD   264   // xt row pitch (u16): +8 pad rotates banks by 4 dwords/row

typedef unsigned short u16;
typedef __attribute__((ext_vector_type(8))) __bf16 bf16x8;
typedef __attribute__((ext_vector_type(4))) float f32x4;

__device__ __forceinline__ float bf2f(u16 u) {
  union { unsigned int w; float f; } v; v.w = ((unsigned int)u) << 16; return v.f;
}
__device__ __forceinline__ u16 f2bf(float f) {
  union { float f; unsigned int w; } v; v.f = f;
  unsigned int r = v.w + 0x7fffu + ((v.w >> 16) & 1u);
  return (u16)(r >> 16);
}
__device__ __forceinline__ float fast_cos(float x) {
  float r = x * 0.15915494309189535f;
  r = r - floorf(r);
  return __builtin_amdgcn_cosf(r);
}
__device__ __forceinline__ void unpack8(bf16x8 v, float* o) {
  const u16* p = (const u16*)&v;
  #pragma unroll
  for (int j = 0; j < 8; ++j) o[j] = bf2f(p[j]);
}

// -------- sniff: float inputs f32 (flag=1) or bf16 (flag=0) --------
__global__ void sniff_kernel(const void* embed, int* flag) {
  int t = threadIdx.x;
  const u16* p = (const u16*)embed;
  int c = 0;
  #pragma unroll
  for (int j = 0; j < 8; ++j) {
    u16 v = p[t * 8 + j];
    int e = (v >> 7) & 0xff;
    c += (e > 128) ? 1 : 0;
  }
  #pragma unroll
  for (int d = 1; d < 64; d <<= 1) c += __shfl_xor(c, d);
  if (t == 0) *flag = (c > 64) ? 1 : 0;
}

// -------- canonicalize all small float params to bf16 in ws --------
struct CanonArgs { const void* p[14]; };

__global__ void canon_kernel(CanonArgs a, const int* __restrict__ flag, u16* __restrict__ dst) {
  const int off[15] = {0, 128, 131200, 131712, 131728, 139920, 140944, 403088,
                       403600, 404112, 404624, 405136, 405648, 406160, 406162};
  int i = blockIdx.x * 256 + threadIdx.x;
  if (i >= 406162) return;
  int isf32 = *flag;
  int s = 0;
  #pragma unroll
  for (int k = 0; k < 13; ++k) s += (i >= off[k + 1]) ? 1 : 0;
  int j = i - off[s];
  u16 v = isf32 ? f2bf(((const float*)a.p[s])[j]) : ((const u16*)a.p[s])[j];
  dst[i] = v;
}

// ---- prep: weights to staging layout [K/8][256][8] (k-chunked, n-major, k-inner) ----
__global__ void prep_kernel(const u16* __restrict__ cw, const u16* __restrict__ l2,
                            u16* __restrict__ cwT, u16* __restrict__ l2T) {
  int id = blockIdx.x * 256 + threadIdx.x;
  if (id < 2 * 256 * 256) {
    int l = id >> 16, rem = id & 65535;
    int kc = rem >> 11, n = (rem >> 3) & 255, kj = rem & 7;
    cwT[id] = cw[l * 65536 + (kc * 8 + kj) * 256 + n];
  } else {
    int j = id - 131072;
    if (j < 2 * 512 * 256) {
      int l = j >> 17, rem = j & 131071;
      int kc = rem >> 11, n = (rem >> 3) & 255, kj = rem & 7;
      l2T[j] = l2[l * 131072 + (kc * 8 + kj) * 256 + n];
    }
  }
}

// ====== MEGA: embed+PE -> [attn GEMM+LN1 -> q -> ffn GEMM+LN2] x2 -> pool ======
// Everything is row-local after embedding; a block owns 64 complete rows in LDS.
__launch_bounds__(256, 2)
__global__ void mega_kernel(const int* __restrict__ tokens, const void* __restrict__ embed,
                            const int* __restrict__ flag, const u16* __restrict__ canon,
                            const u16* __restrict__ cwT, const u16* __restrict__ l2T,
                            float* __restrict__ pooled) {
  __shared__ u16 xt[64 * XLD];          // 33792 B persistent x tile
  __shared__ union {
    struct { u16 Bt[256 * 64]; u16 At[64 * 64]; u16 qs[64 * 8]; } k;  // 41984 B
    struct { float2 sstat[64][5]; float2 sms[64]; } ln;               // 3072 B
  } sh;
  __shared__ u16 thL[64];               // 128 B

  const int tid = threadIdx.x;
  const int wave = tid >> 6, lane = tid & 63;
  const int fr = lane & 15, fq = lane >> 4;
  const int m0 = blockIdx.x * 64;
  const int isf32 = *flag;

  int cols[4];
  #pragma unroll
  for (int ni = 0; ni < 4; ++ni) cols[ni] = wave * 64 + ni * 16 + fr;

  // ---------- embed + positional encoding -> xt (FULL 64x256 coverage: 8 its) ----------
  {
    const float c0 = 9.210340371976184f / 128.f;   // ln(10000)/128
    const float inv2pi = 0.15915494309189535f;
    #pragma unroll
    for (int it = 0; it < 8; ++it) {
      int c = it * 256 + tid;
      int r = c >> 5, e8 = c & 31;       // 64 rows x 32 8-elem chunks = 2048 writes
      int tok = tokens[m0 + r];
      float ev[8];
      if (isf32) {
        const float* ep = (const float*)embed + (size_t)tok * EDIM + e8 * 8;
        float4 a = *(const float4*)ep, b = *(const float4*)(ep + 4);
        ev[0]=a.x; ev[1]=a.y; ev[2]=a.z; ev[3]=a.w; ev[4]=b.x; ev[5]=b.y; ev[6]=b.z; ev[7]=b.w;
      } else {
        const u16* ep = (const u16*)embed + (size_t)tok * EDIM + e8 * 8;
        uint4 v = *(const uint4*)ep;
        unpack8(*(const bf16x8*)&v, ev);
      }
      int s = (m0 + r) & (SEQ - 1);
      u16 o[8];
      #pragma unroll
      for (int j = 0; j < 8; ++j) {
        int e = e8 * 8 + j, i = e >> 1;
        float rev = (float)s * (__expf(-(float)i * c0) * inv2pi);
        rev = rev - floorf(rev);
        float pe = (e & 1) ? __builtin_amdgcn_cosf(rev) : __builtin_amdgcn_sinf(rev);
        o[j] = f2bf(ev[j] + pe);
      }
      *(uint4*)(xt + r * XLD + e8 * 8) = *(const uint4*)o;
    }
  }
  __syncthreads();

  f32x4 acc[4][4];

  auto mfma_step = [&]() {
    const bf16x8* Av = (const bf16x8*)sh.k.At;
    const bf16x8* Bv = (const bf16x8*)sh.k.Bt;
    #pragma unroll
    for (int ks = 0; ks < 2; ++ks) {
      const int kc = ks * 4 + fq;
      bf16x8 af[4], bfv[4];
      #pragma unroll
      for (int mi = 0; mi < 4; ++mi) af[mi] = Av[kc * 64 + ((mi * 16 + fr) ^ kc)];
      #pragma unroll
      for (int ni = 0; ni < 4; ++ni) bfv[ni] = Bv[kc * 256 + cols[ni]];
      #pragma unroll
      for (int mi = 0; mi < 4; ++mi)
        #pragma unroll
        for (int ni = 0; ni < 4; ++ni)
          acc[mi][ni] = __builtin_amdgcn_mfma_f32_16x16x32_bf16(af[mi], bfv[ni], acc[mi][ni], 0, 0, 0);
    }
  };

  // bias + residual + LN over acc (C/D: row=mi*16+fq*4+rg, col=cols[ni]); xt updated in place
  auto epilogue = [&](const u16* bias, const u16* gamma, const u16* beta) {
    float bcol[4];
    #pragma unroll
    for (int ni = 0; ni < 4; ++ni) bcol[ni] = bf2f(bias[cols[ni]]);
    #pragma unroll
    for (int mi = 0; mi < 4; ++mi)
      #pragma unroll
      for (int rg = 0; rg < 4; ++rg) {
        int lrow = mi * 16 + fq * 4 + rg;
        #pragma unroll
        for (int ni = 0; ni < 4; ++ni)
          acc[mi][ni][rg] += bf2f(xt[lrow * XLD + cols[ni]]) + bcol[ni];
      }
    float sr[4][4], sq[4][4];
    #pragma unroll
    for (int mi = 0; mi < 4; ++mi)
      #pragma unroll
      for (int rg = 0; rg < 4; ++rg) {
        float a = 0.f, b = 0.f;
        #pragma unroll
        for (int ni = 0; ni < 4; ++ni) { float t2 = acc[mi][ni][rg]; a += t2; b += t2 * t2; }
        sr[mi][rg] = a; sq[mi][rg] = b;
      }
    #pragma unroll
    for (int d = 1; d < 16; d <<= 1)
      #pragma unroll
      for (int mi = 0; mi < 4; ++mi)
        #pragma unroll
        for (int rg = 0; rg < 4; ++rg) {
          sr[mi][rg] += __shfl_xor(sr[mi][rg], d);
          sq[mi][rg] += __shfl_xor(sq[mi][rg], d);
        }
    if (fr == 0) {
      #pragma unroll
      for (int mi = 0; mi < 4; ++mi)
        #pragma unroll
        for (int rg = 0; rg < 4; ++rg)
          sh.ln.sstat[mi * 16 + fq * 4 + rg][wave] = float2{sr[mi][rg], sq[mi][rg]};
    }
    __syncthreads();
    if (tid < 64) {
      float s = 0.f, s2 = 0.f;
      #pragma unroll
      for (int w = 0; w < 4; ++w) { float2 p = sh.ln.sstat[tid][w]; s += p.x; s2 += p.y; }
      float mean = s * (1.f / 256.f);
      float var = fmaxf(s2 * (1.f / 256.f) - mean * mean, 0.f);
      sh.ln.sms[tid] = float2{mean, rsqrtf(var + 1e-5f)};
    }
    __syncthreads();
    float gcol[4], btc[4];
    #pragma unroll
    for (int ni = 0; ni < 4; ++ni) { gcol[ni] = bf2f(gamma[cols[ni]]); btc[ni] = bf2f(beta[cols[ni]]); }
    #pragma unroll
    for (int mi = 0; mi < 4; ++mi)
      #pragma unroll
      for (int rg = 0; rg < 4; ++rg) {
        int lrow = mi * 16 + fq * 4 + rg;
        float2 ms = sh.ln.sms[lrow];
        #pragma unroll
        for (int ni = 0; ni < 4; ++ni) {
          float o = (acc[mi][ni][rg] - ms.x) * ms.y * gcol[ni] + btc[ni];
          xt[lrow * XLD + cols[ni]] = f2bf(o);
        }
      }
    __syncthreads();
  };

  for (int l = 0; l < 2; ++l) {
    // ---------- attn: acc = cos(xt + theta) @ cwT ----------
    if (tid < 8) ((uint4*)thL)[tid] = ((const uint4*)(canon + l * 64))[tid];
    __syncthreads();
    #pragma unroll
    for (int i = 0; i < 4; ++i)
      #pragma unroll
      for (int j = 0; j < 4; ++j) acc[i][j] = {0.f, 0.f, 0.f, 0.f};
    {
      const u16* Bbase = cwT + l * 65536;
      for (int k0 = 0; k0 < 256; k0 += 64) {
        const u16* bsrc = Bbase + (k0 >> 3) * 2048;
        #pragma unroll
        for (int it = 0; it < 8; ++it) {
          int c = tid + it * 256;
          __builtin_amdgcn_global_load_lds(
              (const __attribute__((address_space(1))) void*)(bsrc + (size_t)c * 8),
              (__attribute__((address_space(3))) void*)(sh.k.Bt + c * 8), 16, 0, 0);
        }
        #pragma unroll
        for (int it = 0; it < 2; ++it) {
          int c = it * 256 + tid;
          int f8 = c >> 6, r = c & 63;       // f8 wave-uniform
          uint4 g = *(const uint4*)(xt + r * XLD + k0 + f8 * 8);
          u16* gp = (u16*)&g;
          #pragma unroll
          for (int j = 0; j < 8; ++j)
            gp[j] = f2bf(fast_cos(bf2f(gp[j]) + bf2f(thL[f8 * 8 + j])));
          ((uint4*)sh.k.At)[f8 * 64 + (r ^ f8)] = g;
        }
        __syncthreads();
        mfma_step();
        __syncthreads();
      }
    }
    epilogue(canon + 131200 + l * 256, canon + 403600 + l * 256, canon + 404112 + l * 256);

    // ---------- q = cos(xt[:, :8]) * cos(ffn_theta) ----------
    #pragma unroll
    for (int rep = 0; rep < 2; ++rep) {
      int idx = tid + rep * 256;
      int r = idx >> 3, n = idx & 7;
      float cth = fast_cos(bf2f(canon[131712 + l * 8 + n]));
      sh.k.qs[r * 8 + n] = f2bf(fast_cos(bf2f(xt[r * XLD + n])) * cth);
    }
    __syncthreads();

    // ---------- ffn: acc = relu(q @ W1 + b1) @ l2T ----------
    #pragma unroll
    for (int i = 0; i < 4; ++i)
      #pragma unroll
      for (int j = 0; j < 4; ++j) acc[i][j] = {0.f, 0.f, 0.f, 0.f};
    {
      const u16* B2 = l2T + l * 131072;
      const u16* w1 = canon + 131728 + l * 4096;
      const u16* b1 = canon + 139920 + l * 512;
      for (int k0 = 0; k0 < 512; k0 += 64) {
        const u16* bsrc = B2 + (k0 >> 3) * 2048;
        #pragma unroll
        for (int it = 0; it < 8; ++it) {
          int c = tid + it * 256;
          __builtin_amdgcn_global_load_lds(
              (const __attribute__((address_space(1))) void*)(bsrc + (size_t)c * 8),
              (__attribute__((address_space(3))) void*)(sh.k.Bt + c * 8), 16, 0, 0);
        }
        #pragma unroll
        for (int it = 0; it < 2; ++it) {
          int c = it * 256 + tid;
          int kc = c >> 6, r = c & 63;       // kc wave-uniform
          int cc = (k0 >> 3) + kc;           // global 8-col chunk of h
          float qf[8], hv[8];
          unpack8(((const bf16x8*)sh.k.qs)[r], qf);
          { uint4 bv = *(const uint4*)(b1 + cc * 8); unpack8(*(const bf16x8*)&bv, hv); }
          #pragma unroll
          for (int n = 0; n < 8; ++n) {
            uint4 wv = *(const uint4*)(w1 + n * 512 + cc * 8);  // wave-uniform, L2-hot
            float wf[8];
            unpack8(*(const bf16x8*)&wv, wf);
            #pragma unroll
            for (int j = 0; j < 8; ++j) hv[j] += qf[n] * wf[j];
          }
          uint4 g; u16* gp = (u16*)&g;
          #pragma unroll
          for (int j = 0; j < 8; ++j) gp[j] = f2bf(fmaxf(hv[j], 0.f));
          ((uint4*)sh.k.At)[kc * 64 + (r ^ kc)] = g;
        }
        __syncthreads();
        mfma_step();
        __syncthreads();
      }
    }
    epilogue(canon + 403088 + l * 256, canon + 404624 + l * 256, canon + 405136 + l * 256);
  }

  // ---------- pool: per-block column sums -> atomicAdd ----------
  {
    float s = 0.f;
    #pragma unroll 8
    for (int r = 0; r < 64; ++r) s += bf2f(xt[r * XLD + tid]);
    atomicAdd(&pooled[(m0 >> 11) * EDIM + tid], s);
  }
}

__global__ void logits_kernel(const float* __restrict__ pooled, const u16* __restrict__ clsw,
                              const u16* __restrict__ clsb, const int* __restrict__ flag,
                              void* __restrict__ out) {
  int t = threadIdx.x;
  int b = t >> 4, sub = t & 15;
  float a0 = 0.f, a1 = 0.f;
  #pragma unroll
  for (int j = 0; j < 16; ++j) {
    int e = sub * 16 + j;
    float p = pooled[b * 256 + e];
    a0 += p * bf2f(clsw[e * 2 + 0]);
    a1 += p * bf2f(clsw[e * 2 + 1]);
  }
  #pragma unroll
  for (int d = 1; d < 16; d <<= 1) {
    a0 += __shfl_xor(a0, d);
    a1 += __shfl_xor(a1, d);
  }
  if (sub == 0) {
    float o0 = a0 * (1.f / 2048.f) + bf2f(clsb[0]);
    float o1 = a1 * (1.f / 2048.f) + bf2f(clsb[1]);
    if (*flag) {
      ((float*)out)[b * 2 + 0] = o0; ((float*)out)[b * 2 + 1] = o1;
    } else {
      ((u16*)out)[b * 2 + 0] = f2bf(o0); ((u16*)out)[b * 2 + 1] = f2bf(o1);
    }
  }
}

extern "C" void kernel_launch(void* const* d_in, const int* in_sizes, int n_in,
                              void* d_out, int out_size, void* d_ws, size_t ws_size,
                              hipStream_t stream) {
  const int* tokens = (const int*)d_in[0];

  char* ws = (char*)d_ws;
  u16*   canon  = (u16*)(ws + 0);              // 812 KB canonical bf16 params
  u16*   cwT    = (u16*)(ws + 1048576);        // 256 KB
  u16*   l2T    = (u16*)(ws + 1310720);        // 512 KB
  float* pooled = (float*)(ws + 1835008);      //  16 KB
  int*   flag   = (int*)(ws + 1851392);        //   4 B

  sniff_kernel<<<1, 64, 0, stream>>>(d_in[1], flag);

  CanonArgs ca;
  for (int i = 0; i < 14; ++i) ca.p[i] = d_in[i + 2];
  canon_kernel<<<1587, 256, 0, stream>>>(ca, flag, canon);

  prep_kernel<<<1536, 256, 0, stream>>>(canon + 128, canon + 140944, cwT, l2T);

  hipMemsetAsync(pooled, 0, NBATCH * EDIM * sizeof(float), stream);

  mega_kernel<<<512, 256, 0, stream>>>(tokens, d_in[1], flag, canon, cwT, l2T, pooled);

  logits_kernel<<<1, 256, 0, stream>>>(pooled, canon + 405648, canon + 406160, flag, d_out);
}